// Round 2
// baseline (606.660 us; speedup 1.0000x reference)
//
#include <hip/hip_runtime.h>
#include <math.h>

#define BATCH 4
#define CIN   512
#define PABN  64
#define HW    4096
#define PROW  4356            // 66*66 padded pixel rows

typedef __attribute__((ext_vector_type(8))) short bfrag;   // 8 bf16
typedef __attribute__((ext_vector_type(4))) float ffrag;   // 4 fp32
#define MFMA(a, b, c) __builtin_amdgcn_mfma_f32_16x16x32_bf16(a, b, c, 0, 0, 0)

__device__ __forceinline__ void gload16(const void* g, void* l) {
    __builtin_amdgcn_global_load_lds(
        (const __attribute__((address_space(1))) unsigned int*)g,
        (__attribute__((address_space(3))) unsigned int*)l, 16, 0, 0);
}

__device__ __forceinline__ unsigned f2bf(float f) {   // fp32 -> bf16 bits, RNE
    unsigned u = __float_as_uint(f);
    return (u + 0x7fffu + ((u >> 16) & 1u)) >> 16;
}

// padded row index for pixel n: (h+1)*66 + (w+1) = n + 2*(n>>6) + 67
__device__ __forceinline__ int prow(int n) { return n + 2 * (n >> 6) + 67; }

// ---------------------------------------------------------------------------
__global__ __launch_bounds__(256) void k_fill0(uint4* __restrict__ p) {
    uint4 z; z.x = z.y = z.z = z.w = 0u;
    p[(size_t)blockIdx.x * 256 + threadIdx.x] = z;
}

// w_top/w_cen [64][512] fp32 -> bf16 (layout kept: [p][i], K=i contiguous)
__global__ __launch_bounds__(256) void k_wpc(const float* __restrict__ wt,
        const float* __restrict__ wc, short* __restrict__ ot, short* __restrict__ oc) {
    const float* src = blockIdx.y ? wc : wt;
    short* dst       = blockIdx.y ? oc : ot;
    int idx = (blockIdx.x * 256 + threadIdx.x) * 4;
    float4 v = *(const float4*)(src + idx);
    uint2 u;
    u.x = f2bf(v.x) | (f2bf(v.y) << 16);
    u.y = f2bf(v.z) | (f2bf(v.w) << 16);
    *(uint2*)(dst + idx) = u;
}

// w [O][I][3][3] fp32 -> wT[k][o][i] bf16
__global__ __launch_bounds__(256) void k_w9(const float* __restrict__ wb,
        const float* __restrict__ wo, short* __restrict__ wbT, short* __restrict__ woT) {
    const float* w = blockIdx.z ? wo : wb;
    short* wT      = blockIdx.z ? woT : wbT;
    int o = blockIdx.x;
    int i = blockIdx.y * 256 + threadIdx.x;
    const float* src = w + ((size_t)o * CIN + i) * 9;
    float v[9];
#pragma unroll
    for (int k = 0; k < 9; k++) v[k] = src[k];
#pragma unroll
    for (int k = 0; k < 9; k++)
        wT[((size_t)k * CIN + o) * CIN + i] = (short)f2bf(v[k]);
}

// ---------------------------------------------------------------------------
// x [B][512][4096] fp32 (ADD: + invZ * O [n][c] fp32, raw-reshape-equivalent) ->
// pixel-major padded bf16 xp [B][4356][512]. Borders pre-zeroed by k_fill0.
// grid (64 pix-tiles, 8 ch-tiles, B)
template <bool ADD>
__global__ __launch_bounds__(256) void k_padT(const float* __restrict__ x,
        const float* __restrict__ Oc, const float* __restrict__ Zp,
        short* __restrict__ xp) {
    __shared__ float Ts[64][68];
    int t = threadIdx.x;
    int n0 = blockIdx.x * 64, c0 = blockIdx.y * 64, b = blockIdx.z;
    float iz = ADD ? (1.0f / Zp[b]) : 1.0f;
    const float* xb = x + ((size_t)b * CIN + c0) * HW;
#pragma unroll
    for (int j = 0; j < 4; j++) {
        int slot = j * 256 + t;
        int r = slot >> 4, col = (slot & 15) * 4;
        float4 v = *(const float4*)(xb + (size_t)r * HW + n0 + col);
        *(float4*)&Ts[r][col] = v;
    }
    __syncthreads();
    short* xpb = xp + (size_t)b * PROW * CIN;
    const float* ob = ADD ? (Oc + (size_t)b * HW * CIN) : nullptr;
#pragma unroll
    for (int j = 0; j < 2; j++) {
        int slot = j * 256 + t;
        int pix = slot >> 3, ch = (slot & 7) * 8;
        int rp = prow(n0 + pix);
        float v[8];
#pragma unroll
        for (int k = 0; k < 8; k++) v[k] = Ts[ch + k][pix];
        if (ADD) {
            const float* os = ob + (size_t)(n0 + pix) * CIN + c0 + ch;
#pragma unroll
            for (int k = 0; k < 8; k += 4) {
                float4 o4 = *(const float4*)(os + k);
                v[k]   += o4.x * iz; v[k+1] += o4.y * iz;
                v[k+2] += o4.z * iz; v[k+3] += o4.w * iz;
            }
        }
        unsigned pk[4];
#pragma unroll
        for (int k = 0; k < 4; k++)
            pk[k] = f2bf(v[2*k]) | (f2bf(v[2*k+1]) << 16);
        *(uint4*)(xpb + (size_t)rp * CIN + c0 + ch) = *(uint4*)pk;
    }
}

// ---------------------------------------------------------------------------
// 1x1 convs: xt/xc[n][p] = sum_i xp[n][i]*w[p][i] + bias.  M=p(64), N=n(64), K=512
// grid (64 n-tiles, 8: b*2+which)
__global__ __launch_bounds__(256) void k_qk(const short* __restrict__ xp,
        const short* __restrict__ wtop, const short* __restrict__ wcen,
        const float* __restrict__ btop, const float* __restrict__ bcen,
        short* __restrict__ xt, short* __restrict__ xc) {
    __shared__ __align__(16) short As[2048];   // w: 64 rows(p) x 32(i)
    __shared__ __align__(16) short Bs[2048];   // x: 64 rows(n) x 32(i)
    int t = threadIdx.x;
    int n0 = blockIdx.x * 64;
    int b = blockIdx.y >> 1, which = blockIdx.y & 1;
    const short* w    = which ? wcen : wtop;
    const float* bias = which ? bcen : btop;
    short* out        = (which ? xc : xt) + (size_t)b * HW * PABN;
    const short* xb   = xp + (size_t)b * PROW * CIN;

    int arow = t >> 2, ach = t & 3;
    int sch = ach ^ ((arow >> 1) & 3);
    int rp = prow(n0 + arow);
    int lane = t & 63, wid = t >> 6, l15 = lane & 15, q = lane >> 4;
    int wm = wid >> 1, wn = wid & 1;
    int cx = (q ^ ((l15 >> 1) & 3)) * 8;
    ffrag acc[2][2] = {};

    for (int i0 = 0; i0 < CIN; i0 += 32) {
        gload16(w  + (size_t)arow * CIN + i0 + sch * 8, As + t * 8);
        gload16(xb + (size_t)rp   * CIN + i0 + sch * 8, Bs + t * 8);
        __syncthreads();
        bfrag a[2], bb[2];
        a[0]  = *(const bfrag*)(As + (wm * 32 + l15) * 32 + cx);
        a[1]  = *(const bfrag*)(As + (wm * 32 + 16 + l15) * 32 + cx);
        bb[0] = *(const bfrag*)(Bs + (wn * 32 + l15) * 32 + cx);
        bb[1] = *(const bfrag*)(Bs + (wn * 32 + 16 + l15) * 32 + cx);
        acc[0][0] = MFMA(a[0], bb[0], acc[0][0]);
        acc[0][1] = MFMA(a[0], bb[1], acc[0][1]);
        acc[1][0] = MFMA(a[1], bb[0], acc[1][0]);
        acc[1][1] = MFMA(a[1], bb[1], acc[1][1]);
        __syncthreads();
    }
#pragma unroll
    for (int mi = 0; mi < 2; mi++) {
        int p = wm * 32 + mi * 16 + q * 4;
        float4 bv = *(const float4*)(bias + p);
#pragma unroll
        for (int ni = 0; ni < 2; ni++) {
            int nn = n0 + wn * 32 + ni * 16 + l15;
            ffrag v = acc[mi][ni];
            uint2 u;
            u.x = f2bf(v.x + bv.x) | (f2bf(v.y + bv.y) << 16);
            u.y = f2bf(v.z + bv.z) | (f2bf(v.w + bv.w) << 16);
            *(uint2*)(out + (size_t)nn * PABN + p) = u;
        }
    }
}

// ---------------------------------------------------------------------------
// conv3x3: out = conv(in, wT) + bias.  M=n(128), N=o(128), K=i over 9 taps.
// grid (32 n-tiles, 4 o-tiles, B)
template <bool FP32OUT>
__global__ __launch_bounds__(256) void k_conv(const short* __restrict__ xin,
        const short* __restrict__ wT, const float* __restrict__ bias,
        void* __restrict__ outv) {
    __shared__ __align__(16) short As[8192];   // pixels: 128 x 64
    __shared__ __align__(16) short Bs[8192];   // weights: 128(o) x 64
    int t = threadIdx.x;
    int n0 = blockIdx.x * 128, o0 = blockIdx.y * 128, b = blockIdx.z;
    const short* xb = xin + (size_t)b * PROW * CIN;
    int lane = t & 63, wid = t >> 6, l15 = lane & 15, q = lane >> 4;
    int wm = wid >> 1, wn = wid & 1;
    int arow = t >> 3, ach = t & 7;
    int sch = ach ^ (arow & 7);
    int pr[4];
#pragma unroll
    for (int j = 0; j < 4; j++) pr[j] = prow(n0 + j * 32 + arow);
    ffrag acc[4][4] = {};

    for (int k9 = 0; k9 < 9; k9++) {
        int kh = k9 / 3, kw = k9 - kh * 3;
        int sh = (kh - 1) * 66 + (kw - 1);
        const short* wk = wT + (size_t)k9 * CIN * CIN;
        for (int i0 = 0; i0 < CIN; i0 += 64) {
#pragma unroll
            for (int j = 0; j < 4; j++) {
                gload16(xb + (size_t)(pr[j] + sh) * CIN + i0 + sch * 8,
                        As + (j * 256 + t) * 8);
                gload16(wk + (size_t)(o0 + j * 32 + arow) * CIN + i0 + sch * 8,
                        Bs + (j * 256 + t) * 8);
            }
            __syncthreads();
#pragma unroll
            for (int kc = 0; kc < 2; kc++) {
                int cx = (((kc * 4 + q) ^ (l15 & 7))) * 8;
                bfrag a[4], bb[4];
#pragma unroll
                for (int mi = 0; mi < 4; mi++)
                    a[mi] = *(const bfrag*)(As + (wm * 64 + mi * 16 + l15) * 64 + cx);
#pragma unroll
                for (int ni = 0; ni < 4; ni++)
                    bb[ni] = *(const bfrag*)(Bs + (wn * 64 + ni * 16 + l15) * 64 + cx);
#pragma unroll
                for (int mi = 0; mi < 4; mi++)
#pragma unroll
                    for (int ni = 0; ni < 4; ni++)
                        acc[mi][ni] = MFMA(a[mi], bb[ni], acc[mi][ni]);
            }
            __syncthreads();
        }
    }
#pragma unroll
    for (int ni = 0; ni < 4; ni++) {
        int o = o0 + wn * 64 + ni * 16 + l15;
        float bv = bias[o];
#pragma unroll
        for (int mi = 0; mi < 4; mi++) {
            int n = n0 + wm * 64 + mi * 16 + q * 4;
            ffrag v = acc[mi][ni];
            if (FP32OUT) {
                float* out = (float*)outv + (size_t)b * CIN * HW;
                *(float4*)(out + (size_t)o * HW + n) =
                    make_float4(v.x + bv, v.y + bv, v.z + bv, v.w + bv);
            } else {
                short* out = (short*)outv + (size_t)b * CIN * HW;
                uint2 u;
                u.x = f2bf(v.x + bv) | (f2bf(v.y + bv) << 16);
                u.y = f2bf(v.z + bv) | (f2bf(v.w + bv) << 16);
                *(uint2*)(out + (size_t)o * HW + n) = u;
            }
        }
    }
}

// ---------------------------------------------------------------------------
// Fused S+PV v2: 256-thr (4-wave) blocks, tile 64n x 256c, 2 blocks/CU.
//   Per iter (m-step 64): merged MFMA cluster {S(it): 8 MFMA, PV(it-1): 32 MFMA}
//   -> barrier -> {XB reg->LDS write, exp->PS, issue next XT gload_lds + XB reg
//   loads, counted vmcnt} -> barrier.  2 barriers/iter; XT dbuf prefetch never
//   drained mid-loop (vmcnt(1)/vmcnt(8)).
// LDS 56 KB: XT[2][64][64] | XB[256][64] single (T14 reg-staged) | PS[64][64]
// (XC staged through PS area in prologue; aS frags live in registers.)
// grid 512 XCD-chunked: each XCD owns one (b,chalf) slice -> XB L2-resident.
__global__ __launch_bounds__(256, 2) void k_fused(const short* __restrict__ xc,
        const short* __restrict__ xt, const short* __restrict__ xb,
        float* __restrict__ O, float* __restrict__ Zbuf) {
    __shared__ __align__(16) short SM[28672];   // 56 KB
    short* XT0 = SM;                  // [2][64][64]  (4096 shorts each)
    short* XBs = SM + 8192;           // [256][64]
    short* PS  = SM + 24576;          // [64][64]

    int bid = blockIdx.x;
    int wg = ((bid & 7) << 6) | (bid >> 3);     // XCD-chunked bijection (512%8==0)
    int b = wg >> 7, chalf = (wg >> 6) & 1, ntile = wg & 63;
    int n0 = ntile * 64, c0 = chalf * 256;
    const short* xcb = xc + (size_t)b * HW * PABN;
    const short* xtb = xt + (size_t)b * HW * PABN;
    const short* xbb = xb + (size_t)b * CIN * HW + (size_t)c0 * HW;

    int t = threadIdx.x;
    int lane = t & 63, wid = t >> 6, l15 = lane & 15, q = lane >> 4;
    // gload_lds staging for 64x64 tiles: rows t>>3 and t>>3+32, chunk t&7
    int srow = t >> 3;
    int sch = (t & 7) ^ (srow & 7);             // pre-swizzled global chunk
    // XB reg staging: 8 rows (t>>3)+32j, LINEAR global chunk t&7, swizzled dest
    int xbr = t >> 3, xbch = t & 7;
    int xbp = xbch ^ (xbr & 7);                 // LDS dest chunk position
    const short* xbsrc = xbb + (size_t)xbr * HW + xbch * 8;

    // ---- prologue: XC -> PS area, XT(0) -> XT0[0], XB(0) -> regs
    gload16(xcb + (size_t)(n0 + srow) * PABN + sch * 8, PS + t * 8);
    gload16(xcb + (size_t)(n0 + srow + 32) * PABN + sch * 8, PS + (256 + t) * 8);
    gload16(xtb + (size_t)srow * PABN + sch * 8, XT0 + t * 8);
    gload16(xtb + (size_t)(srow + 32) * PABN + sch * 8, XT0 + (256 + t) * 8);
    uint4 xreg[8];
#pragma unroll
    for (int j = 0; j < 8; j++)
        xreg[j] = *(const uint4*)(xbsrc + (size_t)(32 * j) * HW);
    asm volatile("s_waitcnt vmcnt(0)" ::: "memory");
    __builtin_amdgcn_s_barrier();
    asm volatile("" ::: "memory");
    bfrag aS[2];                                // loop-invariant xc A-frags
#pragma unroll
    for (int kc = 0; kc < 2; kc++)
        aS[kc] = *(const bfrag*)(PS + (wid * 16 + l15) * 64
                                 + ((kc * 4 + q) ^ (l15 & 7)) * 8);
    asm volatile("s_waitcnt lgkmcnt(0)" ::: "memory");
    __builtin_amdgcn_s_barrier();
    asm volatile("" ::: "memory");

    ffrag acc[4][4] = {};
    float zacc = 0.f;
    int nrow = wid * 16 + q * 4;

    for (int it = 0; it < 64; ++it) {
        int cur = it & 1;
        const short* XTc = XT0 + cur * 4096;
        if (it < 63) {                          // prefetch next XT tile early
            int m1 = (it + 1) * 64, nxt = cur ^ 1;
            gload16(xtb + (size_t)(m1 + srow) * PABN + sch * 8,
                    XT0 + nxt * 4096 + t * 8);
            gload16(xtb + (size_t)(m1 + srow + 32) * PABN + sch * 8,
                    XT0 + nxt * 4096 + (256 + t) * 8);
        }
        // ---- merged MFMA cluster: S(it) + PV(it-1)
        ffrag s[4] = {};
        __builtin_amdgcn_s_setprio(1);
#pragma unroll
        for (int ni = 0; ni < 4; ni++)
#pragma unroll
            for (int kc = 0; kc < 2; kc++) {
                bfrag bf = *(const bfrag*)(XTc + (ni * 16 + l15) * 64
                                           + ((kc * 4 + q) ^ (l15 & 7)) * 8);
                s[ni] = MFMA(aS[kc], bf, s[ni]);
            }
        if (it > 0) {
#pragma unroll
            for (int kc = 0; kc < 2; kc++) {
                int cx = ((kc * 4 + q) ^ (l15 & 7)) * 8;
                bfrag av[4], bv[4];
#pragma unroll
                for (int ci = 0; ci < 4; ci++)
                    av[ci] = *(const bfrag*)(XBs + (wid * 64 + ci * 16 + l15) * 64 + cx);
#pragma unroll
                for (int nj = 0; nj < 4; nj++)
                    bv[nj] = *(const bfrag*)(PS + (nj * 16 + l15) * 64 + cx);
#pragma unroll
                for (int ci = 0; ci < 4; ci++)
#pragma unroll
                    for (int nj = 0; nj < 4; nj++)
                        acc[ci][nj] = MFMA(av[ci], bv[nj], acc[ci][nj]);
            }
        }
        __builtin_amdgcn_s_setprio(0);
        __builtin_amdgcn_s_barrier();           // b1: PS/XB cluster reads done
        asm volatile("" ::: "memory");
        if (it < 63) asm volatile("s_waitcnt vmcnt(1)" ::: "memory");  // XB(it) in
        else         asm volatile("s_waitcnt vmcnt(0)" ::: "memory");
#pragma unroll
        for (int j = 0; j < 8; j++)             // XB(it) regs -> LDS (swizzled dest)
            *(uint4*)(XBs + (size_t)(xbr + 32 * j) * 64 + xbp * 8) = xreg[j];
        // exp + PS write (chunk-swizzled)
#pragma unroll
        for (int ni = 0; ni < 4; ni++) {
            int cc = ni * 2 + (l15 >> 3), jj = l15 & 7;
#pragma unroll
            for (int r = 0; r < 4; r++) {
                float e = __expf(s[ni][r]);
                zacc += e;
                PS[(nrow + r) * 64 + (cc ^ ((nrow + r) & 7)) * 8 + jj] =
                    (short)f2bf(e);
            }
        }
        if (it < 63) {                          // issue XB(it+1) reg loads
            const short* src = xbsrc + (size_t)(it + 1) * 64;
#pragma unroll
            for (int j = 0; j < 8; j++)
                xreg[j] = *(const uint4*)(src + (size_t)(32 * j) * HW);
            asm volatile("s_waitcnt vmcnt(8) lgkmcnt(0)" ::: "memory"); // XT landed
        } else {
            asm volatile("s_waitcnt lgkmcnt(0)" ::: "memory");
        }
        __builtin_amdgcn_s_barrier();           // b2: PS(it)/XB(it) visible
        asm volatile("" ::: "memory");
    }
    // ---- final PV(63)
    {
#pragma unroll
        for (int kc = 0; kc < 2; kc++) {
            int cx = ((kc * 4 + q) ^ (l15 & 7)) * 8;
            bfrag av[4], bv[4];
#pragma unroll
            for (int ci = 0; ci < 4; ci++)
                av[ci] = *(const bfrag*)(XBs + (wid * 64 + ci * 16 + l15) * 64 + cx);
#pragma unroll
            for (int nj = 0; nj < 4; nj++)
                bv[nj] = *(const bfrag*)(PS + (nj * 16 + l15) * 64 + cx);
#pragma unroll
            for (int ci = 0; ci < 4; ci++)
#pragma unroll
                for (int nj = 0; nj < 4; nj++)
                    acc[ci][nj] = MFMA(av[ci], bv[nj], acc[ci][nj]);
        }
    }
    // ---- z reduce (chalf 0 blocks only; both halves computed identical S)
#pragma unroll
    for (int off = 32; off > 0; off >>= 1) zacc += __shfl_down(zacc, off, 64);
    __syncthreads();
    float* red = (float*)PS;                    // PS dead; reuse
    if (lane == 0) red[wid] = zacc;
    __syncthreads();
    if (chalf == 0 && t == 0)
        Zbuf[b * 64 + ntile] = red[0] + red[1] + red[2] + red[3];
    // ---- O store (unscaled fp32, [n][c]; invZ applied in k_padT<true>)
    float* Ob = O + (size_t)b * HW * CIN;
#pragma unroll
    for (int ci = 0; ci < 4; ci++)
#pragma unroll
        for (int nj = 0; nj < 4; nj++) {
            int n = n0 + nj * 16 + l15;
            int c = c0 + wid * 64 + ci * 16 + q * 4;
            ffrag v = acc[ci][nj];
            *(float4*)(Ob + (size_t)n * CIN + c) =
                make_float4(v.x, v.y, v.z, v.w);
        }
}

// ---------------------------------------------------------------------------
// Reduce Zbuf[b][0..63] -> Z[b]. 1 block, 256 thr (wave per batch).
__global__ __launch_bounds__(256) void k_redz(const float* __restrict__ Zbuf,
        float* __restrict__ Z) {
    int wid = threadIdx.x >> 6, lane = threadIdx.x & 63;
    float s = Zbuf[wid * 64 + lane];
#pragma unroll
    for (int off = 32; off > 0; off >>= 1) s += __shfl_down(s, off, 64);
    if (lane == 0) Z[wid] = s;
}

// ---------------------------------------------------------------------------
extern "C" void kernel_launch(void* const* d_in, const int* in_sizes, int n_in,
                              void* d_out, int out_size, void* d_ws, size_t ws_size,
                              hipStream_t stream) {
    const float* x     = (const float*)d_in[0];
    const float* w_top = (const float*)d_in[1];
    const float* b_top = (const float*)d_in[2];
    const float* w_cen = (const float*)d_in[3];
    const float* b_cen = (const float*)d_in[4];
    const float* w_bot = (const float*)d_in[5];
    const float* b_bot = (const float*)d_in[6];
    const float* w_out = (const float*)d_in[7];
    const float* b_out = (const float*)d_in[8];

    char* W = (char*)d_ws;
    short* xp   = (short*)(W);               // 17,842,176 B (also reused as yp)
    short* xt   = (short*)(W + 17842176);    //  2,097,152
    short* xc   = (short*)(W + 19939328);    //  2,097,152
    short* wtb  = (short*)(W + 22036480);    //     65,536
    short* wcb  = (short*)(W + 22102016);    //     65,536
    short* wbT  = (short*)(W + 22167552);    //  4,718,592
    short* woT  = (short*)(W + 26886144);    //  4,718,592
    short* xbc  = (short*)(W + 31604736);    // 16,777,216
    float* O    = (float*)(W + 48381952);    // 33,554,432 (unscaled PV output)
    float* Z    = (float*)(W + 81936384);    //        512
    float* Zbuf = (float*)(W + 81936896);    //     16,384 (uses 256 floats)

    k_fill0<<<4356, 256, 0, stream>>>((uint4*)xp);           // zero padded buffer
    k_wpc<<<dim3(32, 2), 256, 0, stream>>>(w_top, w_cen, wtb, wcb);
    k_w9<<<dim3(512, 2, 2), 256, 0, stream>>>(w_bot, w_out, wbT, woT);
    k_padT<false><<<dim3(64, 8, BATCH), 256, 0, stream>>>(x, nullptr, nullptr, xp);
    k_qk<<<dim3(64, 8), 256, 0, stream>>>(xp, wtb, wcb, b_top, b_cen, xt, xc);
    k_conv<false><<<dim3(32, 4, BATCH), 256, 0, stream>>>(xp, wbT, b_bot, xbc);
    k_fused<<<dim3(512), 256, 0, stream>>>(xc, xt, xbc, O, Zbuf);
    k_redz<<<1, 256, 0, stream>>>(Zbuf, Z);
    k_padT<true><<<dim3(64, 8, BATCH), 256, 0, stream>>>(x, O, Z, xp);  // y -> xp
    k_conv<true><<<dim3(32, 4, BATCH), 256, 0, stream>>>(xp, woT, b_out, (float*)d_out);
}

// Round 3
// 397.639 us; speedup vs baseline: 1.5257x; 1.5257x over previous
//
#include <hip/hip_runtime.h>
#include <math.h>

#define BATCH 4
#define CIN   512
#define PABN  64
#define HW    4096
#define PROW  4356            // 66*66 padded pixel rows

typedef __attribute__((ext_vector_type(8))) short bfrag;   // 8 bf16
typedef __attribute__((ext_vector_type(4))) float ffrag;   // 4 fp32
#define MFMA(a, b, c) __builtin_amdgcn_mfma_f32_16x16x32_bf16(a, b, c, 0, 0, 0)

__device__ __forceinline__ void gload16(const void* g, void* l) {
    __builtin_amdgcn_global_load_lds(
        (const __attribute__((address_space(1))) unsigned int*)g,
        (__attribute__((address_space(3))) unsigned int*)l, 16, 0, 0);
}

__device__ __forceinline__ unsigned f2bf(float f) {   // fp32 -> bf16 bits, RNE
    unsigned u = __float_as_uint(f);
    return (u + 0x7fffu + ((u >> 16) & 1u)) >> 16;
}

// padded row index for pixel n: (h+1)*66 + (w+1) = n + 2*(n>>6) + 67
__device__ __forceinline__ int prow(int n) { return n + 2 * (n >> 6) + 67; }

// ---------------------------------------------------------------------------
__global__ __launch_bounds__(256) void k_fill0(uint4* __restrict__ p) {
    uint4 z; z.x = z.y = z.z = z.w = 0u;
    p[(size_t)blockIdx.x * 256 + threadIdx.x] = z;
}

// w_top/w_cen [64][512] fp32 -> bf16 (layout kept: [p][i], K=i contiguous)
__global__ __launch_bounds__(256) void k_wpc(const float* __restrict__ wt,
        const float* __restrict__ wc, short* __restrict__ ot, short* __restrict__ oc) {
    const float* src = blockIdx.y ? wc : wt;
    short* dst       = blockIdx.y ? oc : ot;
    int idx = (blockIdx.x * 256 + threadIdx.x) * 4;
    float4 v = *(const float4*)(src + idx);
    uint2 u;
    u.x = f2bf(v.x) | (f2bf(v.y) << 16);
    u.y = f2bf(v.z) | (f2bf(v.w) << 16);
    *(uint2*)(dst + idx) = u;
}

// w [O][I][3][3] fp32 -> wT[k][o][i] bf16
__global__ __launch_bounds__(256) void k_w9(const float* __restrict__ wb,
        const float* __restrict__ wo, short* __restrict__ wbT, short* __restrict__ woT) {
    const float* w = blockIdx.z ? wo : wb;
    short* wT      = blockIdx.z ? woT : wbT;
    int o = blockIdx.x;
    int i = blockIdx.y * 256 + threadIdx.x;
    const float* src = w + ((size_t)o * CIN + i) * 9;
    float v[9];
#pragma unroll
    for (int k = 0; k < 9; k++) v[k] = src[k];
#pragma unroll
    for (int k = 0; k < 9; k++)
        wT[((size_t)k * CIN + o) * CIN + i] = (short)f2bf(v[k]);
}

// ---------------------------------------------------------------------------
// x [B][512][4096] fp32 (ADD: + invZ * O [n][c] fp32, raw-reshape-equivalent) ->
// pixel-major padded bf16 xp [B][4356][512]. Borders pre-zeroed by k_fill0.
// grid (64 pix-tiles, 8 ch-tiles, B)
template <bool ADD>
__global__ __launch_bounds__(256) void k_padT(const float* __restrict__ x,
        const float* __restrict__ Oc, const float* __restrict__ Zp,
        short* __restrict__ xp) {
    __shared__ float Ts[64][68];
    int t = threadIdx.x;
    int n0 = blockIdx.x * 64, c0 = blockIdx.y * 64, b = blockIdx.z;
    float iz = ADD ? (1.0f / Zp[b]) : 1.0f;
    const float* xb = x + ((size_t)b * CIN + c0) * HW;
#pragma unroll
    for (int j = 0; j < 4; j++) {
        int slot = j * 256 + t;
        int r = slot >> 4, col = (slot & 15) * 4;
        float4 v = *(const float4*)(xb + (size_t)r * HW + n0 + col);
        *(float4*)&Ts[r][col] = v;
    }
    __syncthreads();
    short* xpb = xp + (size_t)b * PROW * CIN;
    const float* ob = ADD ? (Oc + (size_t)b * HW * CIN) : nullptr;
#pragma unroll
    for (int j = 0; j < 2; j++) {
        int slot = j * 256 + t;
        int pix = slot >> 3, ch = (slot & 7) * 8;
        int rp = prow(n0 + pix);
        float v[8];
#pragma unroll
        for (int k = 0; k < 8; k++) v[k] = Ts[ch + k][pix];
        if (ADD) {
            const float* os = ob + (size_t)(n0 + pix) * CIN + c0 + ch;
#pragma unroll
            for (int k = 0; k < 8; k += 4) {
                float4 o4 = *(const float4*)(os + k);
                v[k]   += o4.x * iz; v[k+1] += o4.y * iz;
                v[k+2] += o4.z * iz; v[k+3] += o4.w * iz;
            }
        }
        unsigned pk[4];
#pragma unroll
        for (int k = 0; k < 4; k++)
            pk[k] = f2bf(v[2*k]) | (f2bf(v[2*k+1]) << 16);
        *(uint4*)(xpb + (size_t)rp * CIN + c0 + ch) = *(uint4*)pk;
    }
}

// ---------------------------------------------------------------------------
// 1x1 convs: xt/xc[n][p] = sum_i xp[n][i]*w[p][i] + bias.  M=p(64), N=n(64), K=512
// grid (64 n-tiles, 8: b*2+which)
__global__ __launch_bounds__(256) void k_qk(const short* __restrict__ xp,
        const short* __restrict__ wtop, const short* __restrict__ wcen,
        const float* __restrict__ btop, const float* __restrict__ bcen,
        short* __restrict__ xt, short* __restrict__ xc) {
    __shared__ __align__(16) short As[2048];   // w: 64 rows(p) x 32(i)
    __shared__ __align__(16) short Bs[2048];   // x: 64 rows(n) x 32(i)
    int t = threadIdx.x;
    int n0 = blockIdx.x * 64;
    int b = blockIdx.y >> 1, which = blockIdx.y & 1;
    const short* w    = which ? wcen : wtop;
    const float* bias = which ? bcen : btop;
    short* out        = (which ? xc : xt) + (size_t)b * HW * PABN;
    const short* xb   = xp + (size_t)b * PROW * CIN;

    int arow = t >> 2, ach = t & 3;
    int sch = ach ^ ((arow >> 1) & 3);
    int rp = prow(n0 + arow);
    int lane = t & 63, wid = t >> 6, l15 = lane & 15, q = lane >> 4;
    int wm = wid >> 1, wn = wid & 1;
    int cx = (q ^ ((l15 >> 1) & 3)) * 8;
    ffrag acc[2][2] = {};

    for (int i0 = 0; i0 < CIN; i0 += 32) {
        gload16(w  + (size_t)arow * CIN + i0 + sch * 8, As + t * 8);
        gload16(xb + (size_t)rp   * CIN + i0 + sch * 8, Bs + t * 8);
        __syncthreads();
        bfrag a[2], bb[2];
        a[0]  = *(const bfrag*)(As + (wm * 32 + l15) * 32 + cx);
        a[1]  = *(const bfrag*)(As + (wm * 32 + 16 + l15) * 32 + cx);
        bb[0] = *(const bfrag*)(Bs + (wn * 32 + l15) * 32 + cx);
        bb[1] = *(const bfrag*)(Bs + (wn * 32 + 16 + l15) * 32 + cx);
        acc[0][0] = MFMA(a[0], bb[0], acc[0][0]);
        acc[0][1] = MFMA(a[0], bb[1], acc[0][1]);
        acc[1][0] = MFMA(a[1], bb[0], acc[1][0]);
        acc[1][1] = MFMA(a[1], bb[1], acc[1][1]);
        __syncthreads();
    }
#pragma unroll
    for (int mi = 0; mi < 2; mi++) {
        int p = wm * 32 + mi * 16 + q * 4;
        float4 bv = *(const float4*)(bias + p);
#pragma unroll
        for (int ni = 0; ni < 2; ni++) {
            int nn = n0 + wn * 32 + ni * 16 + l15;
            ffrag v = acc[mi][ni];
            uint2 u;
            u.x = f2bf(v.x + bv.x) | (f2bf(v.y + bv.y) << 16);
            u.y = f2bf(v.z + bv.z) | (f2bf(v.w + bv.w) << 16);
            *(uint2*)(out + (size_t)nn * PABN + p) = u;
        }
    }
}

// ---------------------------------------------------------------------------
// conv3x3: out = conv(in, wT) + bias.  M=n(128), N=o(128), K=i over 9 taps.
// grid (32 n-tiles, 4 o-tiles, B)
template <bool FP32OUT>
__global__ __launch_bounds__(256) void k_conv(const short* __restrict__ xin,
        const short* __restrict__ wT, const float* __restrict__ bias,
        void* __restrict__ outv) {
    __shared__ __align__(16) short As[8192];   // pixels: 128 x 64
    __shared__ __align__(16) short Bs[8192];   // weights: 128(o) x 64
    int t = threadIdx.x;
    int n0 = blockIdx.x * 128, o0 = blockIdx.y * 128, b = blockIdx.z;
    const short* xb = xin + (size_t)b * PROW * CIN;
    int lane = t & 63, wid = t >> 6, l15 = lane & 15, q = lane >> 4;
    int wm = wid >> 1, wn = wid & 1;
    int arow = t >> 3, ach = t & 7;
    int sch = ach ^ (arow & 7);
    int pr[4];
#pragma unroll
    for (int j = 0; j < 4; j++) pr[j] = prow(n0 + j * 32 + arow);
    ffrag acc[4][4] = {};

    for (int k9 = 0; k9 < 9; k9++) {
        int kh = k9 / 3, kw = k9 - kh * 3;
        int sh = (kh - 1) * 66 + (kw - 1);
        const short* wk = wT + (size_t)k9 * CIN * CIN;
        for (int i0 = 0; i0 < CIN; i0 += 64) {
#pragma unroll
            for (int j = 0; j < 4; j++) {
                gload16(xb + (size_t)(pr[j] + sh) * CIN + i0 + sch * 8,
                        As + (j * 256 + t) * 8);
                gload16(wk + (size_t)(o0 + j * 32 + arow) * CIN + i0 + sch * 8,
                        Bs + (j * 256 + t) * 8);
            }
            __syncthreads();
#pragma unroll
            for (int kc = 0; kc < 2; kc++) {
                int cx = (((kc * 4 + q) ^ (l15 & 7))) * 8;
                bfrag a[4], bb[4];
#pragma unroll
                for (int mi = 0; mi < 4; mi++)
                    a[mi] = *(const bfrag*)(As + (wm * 64 + mi * 16 + l15) * 64 + cx);
#pragma unroll
                for (int ni = 0; ni < 4; ni++)
                    bb[ni] = *(const bfrag*)(Bs + (wn * 64 + ni * 16 + l15) * 64 + cx);
#pragma unroll
                for (int mi = 0; mi < 4; mi++)
#pragma unroll
                    for (int ni = 0; ni < 4; ni++)
                        acc[mi][ni] = MFMA(a[mi], bb[ni], acc[mi][ni]);
            }
            __syncthreads();
        }
    }
#pragma unroll
    for (int ni = 0; ni < 4; ni++) {
        int o = o0 + wn * 64 + ni * 16 + l15;
        float bv = bias[o];
#pragma unroll
        for (int mi = 0; mi < 4; mi++) {
            int n = n0 + wm * 64 + mi * 16 + q * 4;
            ffrag v = acc[mi][ni];
            if (FP32OUT) {
                float* out = (float*)outv + (size_t)b * CIN * HW;
                *(float4*)(out + (size_t)o * HW + n) =
                    make_float4(v.x + bv, v.y + bv, v.z + bv, v.w + bv);
            } else {
                short* out = (short*)outv + (size_t)b * CIN * HW;
                uint2 u;
                u.x = f2bf(v.x + bv) | (f2bf(v.y + bv) << 16);
                u.y = f2bf(v.z + bv) | (f2bf(v.w + bv) << 16);
                *(uint2*)(out + (size_t)o * HW + n) = u;
            }
        }
    }
}

// ---------------------------------------------------------------------------
// Fused S+PV v3: 256-thr (4-wave) blocks, tile 64n x 256c, 2 blocks/CU (80 KB).
//   XB staged via global_load_lds DOUBLE buffer (zero VGPR); XT reg-staged
//   (2 uint4 only) into a single 8 KB buffer; PS 8 KB. No big reg arrays ->
//   no scratch spills (v2 lesson: 32-VGPR staging array spilled, 250 MB scratch).
//   Per iter: issue XT(it+1) regs (oldest) then XB(it) gload_lds x8; MFMA
//   cluster {S(it) 8 + PV(it-1) 32}; B1; vmcnt(8) -> ds_write XT; exp->PS;
//   vmcnt(0) (XB landed, issued ~cluster ago) ; B2 publishes PS/XT/XB.
// grid 512 XCD-chunked: each XCD owns one (b,chalf) slice -> xb L2-resident.
__global__ __launch_bounds__(256, 2) void k_fused(const short* __restrict__ xc,
        const short* __restrict__ xt, const short* __restrict__ xb,
        float* __restrict__ O, float* __restrict__ Zbuf) {
    __shared__ __align__(16) short SM[40960];   // 81920 B exactly (512-mult)
    short* XT  = SM;                  // [64][64]     single, reg-prefetched
    short* XB0 = SM + 4096;           // [2][256][64] dbuf via gload_lds
    short* PS  = SM + 36864;          // [64][64]

    int bid = blockIdx.x;
    int wg = ((bid & 7) << 6) | (bid >> 3);     // XCD-chunked bijection (512%8==0)
    int b = wg >> 7, chalf = (wg >> 6) & 1, ntile = wg & 63;
    int n0 = ntile * 64, c0 = chalf * 256;
    const short* xcb = xc + (size_t)b * HW * PABN;
    const short* xtb = xt + (size_t)b * HW * PABN;
    const short* xbb = xb + (size_t)b * CIN * HW + (size_t)c0 * HW;

    int t = threadIdx.x;
    int lane = t & 63, wid = t >> 6, l15 = lane & 15, q = lane >> 4;
    int srow = t >> 3;                 // staging row 0..31
    int lch = t & 7;                   // linear chunk (reg path)
    int sch = lch ^ (srow & 7);        // pre-swizzled chunk (gload_lds path)

    // ---- prologue: XC -> PS area, XT(0) -> XT (both swizzled via source)
    gload16(xcb + (size_t)(n0 + srow) * PABN + sch * 8, PS + t * 8);
    gload16(xcb + (size_t)(n0 + srow + 32) * PABN + sch * 8, PS + (256 + t) * 8);
    gload16(xtb + (size_t)srow * PABN + sch * 8, XT + t * 8);
    gload16(xtb + (size_t)(srow + 32) * PABN + sch * 8, XT + (256 + t) * 8);
    asm volatile("s_waitcnt vmcnt(0)" ::: "memory");
    __builtin_amdgcn_s_barrier();
    asm volatile("" ::: "memory");
    bfrag aS[2];                                // loop-invariant xc A-frags
#pragma unroll
    for (int kc = 0; kc < 2; kc++)
        aS[kc] = *(const bfrag*)(PS + (wid * 16 + l15) * 64
                                 + ((kc * 4 + q) ^ (l15 & 7)) * 8);
    asm volatile("s_waitcnt lgkmcnt(0)" ::: "memory");
    __builtin_amdgcn_s_barrier();               // PS now reusable
    asm volatile("" ::: "memory");

    ffrag acc[4][4] = {};
    float zacc = 0.f;
    int nrow = wid * 16 + q * 4;
    uint4 xt0, xt1;

    for (int it = 0; it < 64; ++it) {
        short* XBcur        = XB0 + (it & 1) * 16384;
        const short* XBprev = XB0 + ((it & 1) ^ 1) * 16384;
        // issue XT(it+1) reg loads FIRST (oldest in vmcnt queue) ...
        if (it < 63) {
            const short* src = xtb + (size_t)((it + 1) * 64 + srow) * PABN + lch * 8;
            xt0 = *(const uint4*)(src);
            xt1 = *(const uint4*)(src + 32 * PABN);
        }
        // ... then XB(it) gload_lds x8 (linear dest, pre-swizzled source)
        {
            const short* src = xbb + (size_t)srow * HW + it * 64 + sch * 8;
#pragma unroll
            for (int j = 0; j < 8; j++)
                gload16(src + (size_t)(32 * j) * HW, XBcur + j * 2048 + t * 8);
        }
        // ---- MFMA cluster: S(it) + PV(it-1)
        ffrag s[4] = {};
        __builtin_amdgcn_s_setprio(1);
#pragma unroll
        for (int ni = 0; ni < 4; ni++)
#pragma unroll
            for (int kc = 0; kc < 2; kc++) {
                bfrag bf = *(const bfrag*)(XT + (ni * 16 + l15) * 64
                                           + ((kc * 4 + q) ^ (l15 & 7)) * 8);
                s[ni] = MFMA(aS[kc], bf, s[ni]);
            }
        if (it > 0) {
#pragma unroll
            for (int kc = 0; kc < 2; kc++) {
                int cx = ((kc * 4 + q) ^ (l15 & 7)) * 8;
                bfrag av[4], bv[4];
#pragma unroll
                for (int ci = 0; ci < 4; ci++)
                    av[ci] = *(const bfrag*)(XBprev + (wid * 64 + ci * 16 + l15) * 64 + cx);
#pragma unroll
                for (int nj = 0; nj < 4; nj++)
                    bv[nj] = *(const bfrag*)(PS + (nj * 16 + l15) * 64 + cx);
#pragma unroll
                for (int ci = 0; ci < 4; ci++)
#pragma unroll
                    for (int nj = 0; nj < 4; nj++)
                        acc[ci][nj] = MFMA(av[ci], bv[nj], acc[ci][nj]);
            }
        }
        __builtin_amdgcn_s_setprio(0);
        __builtin_amdgcn_s_barrier();           // B1: cluster reads of PS/XT done
        asm volatile("" ::: "memory");
        if (it < 63) {                          // XT(it+1) regs -> LDS (swizzled)
            asm volatile("s_waitcnt vmcnt(8)" ::: "memory");  // retires XT2 (oldest)
            *(uint4*)(XT + srow * 64 + sch * 8) = xt0;
            *(uint4*)(XT + (srow + 32) * 64 + sch * 8) = xt1;
        }
        // exp + PS(it) write (chunk-swizzled)
#pragma unroll
        for (int ni = 0; ni < 4; ni++) {
            int cc = ni * 2 + (l15 >> 3), jj = l15 & 7;
#pragma unroll
            for (int r = 0; r < 4; r++) {
                float e = __expf(s[ni][r]);
                zacc += e;
                PS[(nrow + r) * 64 + (cc ^ ((nrow + r) & 7)) * 8 + jj] =
                    (short)f2bf(e);
            }
        }
        asm volatile("s_waitcnt vmcnt(0) lgkmcnt(0)" ::: "memory"); // XB(it) landed
        __builtin_amdgcn_s_barrier();           // B2: publishes PS(it),XT(it+1),XB(it)
        asm volatile("" ::: "memory");
    }
    // ---- final PV(63): XB[1], PS(63)
    {
        const short* XBlast = XB0 + 16384;
#pragma unroll
        for (int kc = 0; kc < 2; kc++) {
            int cx = ((kc * 4 + q) ^ (l15 & 7)) * 8;
            bfrag av[4], bv[4];
#pragma unroll
            for (int ci = 0; ci < 4; ci++)
                av[ci] = *(const bfrag*)(XBlast + (wid * 64 + ci * 16 + l15) * 64 + cx);
#pragma unroll
            for (int nj = 0; nj < 4; nj++)
                bv[nj] = *(const bfrag*)(PS + (nj * 16 + l15) * 64 + cx);
#pragma unroll
            for (int ci = 0; ci < 4; ci++)
#pragma unroll
                for (int nj = 0; nj < 4; nj++)
                    acc[ci][nj] = MFMA(av[ci], bv[nj], acc[ci][nj]);
        }
    }
    // ---- z reduce (chalf 0 blocks only; both halves computed identical S)
#pragma unroll
    for (int off = 32; off > 0; off >>= 1) zacc += __shfl_down(zacc, off, 64);
    __syncthreads();                            // PV reads of PS done
    float* red = (float*)PS;                    // PS dead; reuse
    if (lane == 0) red[wid] = zacc;
    __syncthreads();
    if (chalf == 0 && t == 0)
        Zbuf[b * 64 + ntile] = red[0] + red[1] + red[2] + red[3];
    // ---- O store (unscaled fp32, [n][c]; invZ applied in k_padT<true>)
    float* Ob = O + (size_t)b * HW * CIN;
#pragma unroll
    for (int ci = 0; ci < 4; ci++)
#pragma unroll
        for (int nj = 0; nj < 4; nj++) {
            int n = n0 + nj * 16 + l15;
            int c = c0 + wid * 64 + ci * 16 + q * 4;
            ffrag v = acc[ci][nj];
            *(float4*)(Ob + (size_t)n * CIN + c) =
                make_float4(v.x, v.y, v.z, v.w);
        }
}

// ---------------------------------------------------------------------------
// Reduce Zbuf[b][0..63] -> Z[b]. 1 block, 256 thr (wave per batch).
__global__ __launch_bounds__(256) void k_redz(const float* __restrict__ Zbuf,
        float* __restrict__ Z) {
    int wid = threadIdx.x >> 6, lane = threadIdx.x & 63;
    float s = Zbuf[wid * 64 + lane];
#pragma unroll
    for (int off = 32; off > 0; off >>= 1) s += __shfl_down(s, off, 64);
    if (lane == 0) Z[wid] = s;
}

// ---------------------------------------------------------------------------
extern "C" void kernel_launch(void* const* d_in, const int* in_sizes, int n_in,
                              void* d_out, int out_size, void* d_ws, size_t ws_size,
                              hipStream_t stream) {
    const float* x     = (const float*)d_in[0];
    const float* w_top = (const float*)d_in[1];
    const float* b_top = (const float*)d_in[2];
    const float* w_cen = (const float*)d_in[3];
    const float* b_cen = (const float*)d_in[4];
    const float* w_bot = (const float*)d_in[5];
    const float* b_bot = (const float*)d_in[6];
    const float* w_out = (const float*)d_in[7];
    const float* b_out = (const float*)d_in[8];

    char* W = (char*)d_ws;
    short* xp   = (short*)(W);               // 17,842,176 B (also reused as yp)
    short* xt   = (short*)(W + 17842176);    //  2,097,152
    short* xc   = (short*)(W + 19939328);    //  2,097,152
    short* wtb  = (short*)(W + 22036480);    //     65,536
    short* wcb  = (short*)(W + 22102016);    //     65,536
    short* wbT  = (short*)(W + 22167552);    //  4,718,592
    short* woT  = (short*)(W + 26886144);    //  4,718,592
    short* xbc  = (short*)(W + 31604736);    // 16,777,216
    float* O    = (float*)(W + 48381952);    // 33,554,432 (unscaled PV output)
    float* Z    = (float*)(W + 81936384);    //        512
    float* Zbuf = (float*)(W + 81936896);    //     16,384 (uses 256 floats)

    k_fill0<<<4356, 256, 0, stream>>>((uint4*)xp);           // zero padded buffer
    k_wpc<<<dim3(32, 2), 256, 0, stream>>>(w_top, w_cen, wtb, wcb);
    k_w9<<<dim3(512, 2, 2), 256, 0, stream>>>(w_bot, w_out, wbT, woT);
    k_padT<false><<<dim3(64, 8, BATCH), 256, 0, stream>>>(x, nullptr, nullptr, xp);
    k_qk<<<dim3(64, 8), 256, 0, stream>>>(xp, wtb, wcb, b_top, b_cen, xt, xc);
    k_conv<false><<<dim3(32, 4, BATCH), 256, 0, stream>>>(xp, wbT, b_bot, xbc);
    k_fused<<<dim3(512), 256, 0, stream>>>(xc, xt, xbc, O, Zbuf);
    k_redz<<<1, 256, 0, stream>>>(Zbuf, Z);
    k_padT<true><<<dim3(64, 8, BATCH), 256, 0, stream>>>(x, O, Z, xp);  // y -> xp
    k_conv<true><<<dim3(32, 4, BATCH), 256, 0, stream>>>(xp, woT, b_out, (float*)d_out);
}